// Round 18
// baseline (200.002 us; speedup 1.0000x reference)
//
#include <hip/hip_runtime.h>
#include <hip/hip_bf16.h>
#include <math.h>

#define N_EDGES 4096
#define NN1 256
#define NN2 128

typedef short v8s __attribute__((ext_vector_type(8)));
typedef float v4f __attribute__((ext_vector_type(4)));

__device__ inline unsigned short f2b(float f){
  union { __hip_bfloat16 h; unsigned short u; } cv;
  cv.h = __float2bfloat16(f);
  return cv.u;
}

// ---------------- reduction helpers ----------------
template<int NT>
__device__ inline float block_sum(float v, float* red, int t){
  red[t] = v; __syncthreads();
  #pragma unroll
  for (int st = NT/2; st > 0; st >>= 1){
    if (t < st) red[t] += red[t+st];
    __syncthreads();
  }
  float r = red[0]; __syncthreads();
  return r;
}
template<int NT>
__device__ inline float block_max(float v, float* red, int t){
  red[t] = v; __syncthreads();
  #pragma unroll
  for (int st = NT/2; st > 0; st >>= 1){
    if (t < st) red[t] = fmaxf(red[t], red[t+st]);
    __syncthreads();
  }
  float r = red[0]; __syncthreads();
  return r;
}
template<int NT>
__device__ inline int block_min_int(int v, int* red, int t){
  red[t] = v; __syncthreads();
  #pragma unroll
  for (int st = NT/2; st > 0; st >>= 1){
    if (t < st) red[t] = min(red[t], red[t+st]);
    __syncthreads();
  }
  int r = red[0]; __syncthreads();
  return r;
}

// ---------------- conv3x3(SAME) via bf16 MFMA implicit GEMM (r13 template + split-K) --
// OUTMODE: 0 = bf16 slab out (pool fused), 1 = f32 org out (pool fused),
//          2 = f32 conv partials [z][COUT][W][W] (no pool/bias; split-K over grid.z).
template<int CHUNKS, int COUT, int CIN, int SSLABS, int BSTR, int OUTMODE>
__global__ __launch_bounds__(256) void conv_mfma(
    const unsigned short* __restrict__ in, const unsigned short* __restrict__ wb,
    const float* __restrict__ bias, unsigned short* __restrict__ outb,
    float* __restrict__ outf,
    int in_row, int in_slab, int out_row, int out_slab)
{
  constexpr int CG = COUT/32;
  __shared__ unsigned short tileb[SSLABS*2600];
  __shared__ unsigned short wldsb[9*32*40];

  const int cg = blockIdx.x % CG, bx = blockIdx.x / CG, by = blockIdx.y;
  const int z = blockIdx.z;
  const int cbase = z*CHUNKS;
  const int tid = threadIdx.x, lane = tid & 63, wv = tid >> 6;
  const int cot = wv >> 1, wp = wv & 1;
  const int ml = lane & 15, g = lane >> 4;

  v4f acc[8];
  #pragma unroll
  for (int t = 0; t < 8; ++t) acc[t] = (v4f){0.f,0.f,0.f,0.f};

  for (int cb = 0; cb < CHUNKS; ++cb){
    if (cb) __syncthreads();
    for (int j = tid; j < SSLABS*324; j += 256){
      int s = j / 324, rem = j - s*324;
      int row = rem / 18, px = rem - row*18;
      int gidx = ((cbase+cb)*SSLABS + s)*in_slab + ((by*16 + row)*in_row + bx*16 + px)*8;
      *(v8s*)&tileb[s*2600 + (row*18+px)*8] = *(const v8s*)&in[gidx];
    }
    for (int j = tid; j < 1152; j += 256){
      int k = j >> 7, rem = j & 127;
      int co = rem >> 2, q = rem & 3;
      int gw = (k*COUT + cg*32 + co)*CIN + (cbase+cb)*32 + q*8;
      *(v8s*)&wldsb[(k*32+co)*40 + q*8] = *(const v8s*)&wb[gw];
    }
    __syncthreads();

    #pragma unroll
    for (int k9 = 0; k9 < 9; ++k9){
      const int ky = k9/3, kx = k9 - 3*(k9/3);
      v8s a = *(const v8s*)&wldsb[(k9*32 + cot*16 + ml)*40 + g*8];
      #pragma unroll
      for (int tt = 0; tt < 8; ++tt){
        int t = wp*8 + tt;
        v8s b = *(const v8s*)&tileb[g*BSTR + ((t+ky)*18 + kx + ml)*8];
        acc[tt] = __builtin_amdgcn_mfma_f32_16x16x32_bf16(a, b, acc[tt], 0, 0, 0);
      }
    }
  }

  const int cob = cg*32 + cot*16 + g*4;
  if (OUTMODE == 2){
    const int W = out_row;
    #pragma unroll
    for (int tt = 0; tt < 8; ++tt){
      int gy = by*16 + wp*8 + tt, gx = bx*16 + ml;
      #pragma unroll
      for (int r = 0; r < 4; ++r)
        outf[((size_t)(z*COUT + cob + r)*W + gy)*W + gx] = acc[tt][r];
    }
    return;
  }

  float b4[4] = {bias[cob], bias[cob+1], bias[cob+2], bias[cob+3]};
  #pragma unroll
  for (int tp = 0; tp < 4; ++tp){
    float m[4];
    #pragma unroll
    for (int r = 0; r < 4; ++r){
      float v = fmaxf(acc[2*tp][r], acc[2*tp+1][r]);
      float o = __shfl_xor(v, 1);
      m[r] = fmaxf(fmaxf(v, o) + b4[r], 0.f);
    }
    if ((lane & 1) == 0){
      int gy = by*8 + wp*4 + tp, gx = bx*8 + (ml >> 1);
      if (OUTMODE == 1){
        #pragma unroll
        for (int r = 0; r < 4; ++r)
          outf[(cob + r)*256 + gy*16 + gx] = m[r];
      } else {
        unsigned int u0 = (unsigned)f2b(m[0]) | ((unsigned)f2b(m[1]) << 16);
        unsigned int u1 = (unsigned)f2b(m[2]) | ((unsigned)f2b(m[3]) << 16);
        int slabo = cob >> 3, sub = (g & 1)*4;
        size_t idx = (size_t)slabo*out_slab + (size_t)((gy+1)*out_row + gx+1)*8 + sub;
        *(uint2*)(outb + idx) = make_uint2(u0, u1);
      }
    }
  }
}

// L4 reduce: sum splits + bias + relu + pool -> bf16 slab
template<int SPLITK>
__global__ __launch_bounds__(256) void reduce_pool_b(
    const float* __restrict__ pbuf, const float* __restrict__ bias,
    unsigned short* __restrict__ outb, int COUT, int H, int W,
    int out_row, int out_slab)
{
  int idx = blockIdx.x*256 + threadIdx.x;
  const int OW = W >> 1, OH = H >> 1;
  if (idx >= COUT*OH*OW) return;
  int px = idx % OW; int t2 = idx / OW; int py = t2 % OH; int cout = t2 / OH;
  size_t base = ((size_t)cout*H + 2*py)*W + 2*px;
  size_t sstr = (size_t)COUT*H*W;
  float s00=0.f, s01=0.f, s10=0.f, s11=0.f;
  #pragma unroll
  for (int s = 0; s < SPLITK; ++s){
    const float* pb = pbuf + s*sstr + base;
    s00 += pb[0]; s01 += pb[1]; s10 += pb[W]; s11 += pb[W+1];
  }
  float m = fmaxf(fmaxf(fmaxf(s00,s01), fmaxf(s10,s11)) + bias[cout], 0.f);
  outb[(size_t)(cout>>3)*out_slab + (size_t)((py+1)*out_row + px+1)*8 + (cout&7)] = f2b(m);
}

// L5 reduce (splitK=8 -> f32 org) + build_adj folded into extra blocks
__global__ __launch_bounds__(256) void reduce5_adj_kernel(
    const float* __restrict__ pbuf, const float* __restrict__ bias,
    float* __restrict__ outf, const int* __restrict__ ei,
    float* __restrict__ adj, float* __restrict__ cnt)
{
  int b = blockIdx.x;
  if (b < 256){
    int idx = b*256 + threadIdx.x;
    const int OW=16, OH=16, W=32, H=32, COUT=256;
    int px = idx % OW; int t2 = idx / OW; int py = t2 % OH; int cout = t2 / OH;
    size_t base = ((size_t)cout*H + 2*py)*W + 2*px;
    size_t sstr = (size_t)COUT*H*W;
    float s00=0.f, s01=0.f, s10=0.f, s11=0.f;
    #pragma unroll
    for (int s = 0; s < 8; ++s){
      const float* pb = pbuf + s*sstr + base;
      s00 += pb[0]; s01 += pb[1]; s10 += pb[W]; s11 += pb[W+1];
    }
    float m = fmaxf(fmaxf(fmaxf(s00,s01), fmaxf(s10,s11)) + bias[cout], 0.f);
    outf[cout*OH*OW + py*OW + px] = m;
  } else {
    int e = (b-256)*256 + threadIdx.x;
    if (e < N_EDGES){
      int sn = ei[e], dn = ei[N_EDGES + e];
      atomicAdd(&adj[sn*NN1 + dn], 1.0f);   // adj zeroed by prep (visible)
      atomicAdd(&cnt[dn], 1.0f);
    }
  }
}

// ---------------- prep: input pack + weight cvt + sage wT + border/adj zero ----------
__global__ __launch_bounds__(256) void prep_kernel(
    const float* __restrict__ src, unsigned short* __restrict__ p0b,
    const float* __restrict__ w1, const float* __restrict__ w2,
    const float* __restrict__ w3, const float* __restrict__ w4,
    const float* __restrict__ w5, unsigned short* __restrict__ wbb,
    const float* __restrict__ a, const float* __restrict__ b2,
    const float* __restrict__ c2, const float* __restrict__ d2,
    float* __restrict__ o, unsigned short* __restrict__ wsb,
    float* __restrict__ adjz)
{
  int b = blockIdx.x, tid = threadIdx.x;
  if (b < 1024){
    int idx = b*256 + tid;
    int y = idx >> 9, x = idx & 511;
    unsigned short v8[8];
    #pragma unroll
    for (int c = 0; c < 5; ++c) v8[c] = f2b(src[c*262144 + y*512 + x]);
    v8[5] = 0; v8[6] = 0; v8[7] = 0;
    *(uint4*)&p0b[((size_t)(y+1)*516 + (x+1))*8] = *(uint4*)v8;
  } else if (b < 1452){
    int j = (b-1024)*256 + tid;
    int co, ci, CO, CIl, CIsrc, dst; const float* w;
    if (j < 1024)      { co=j>>5;        ci=j&31;        w=w1; CIsrc=5;   CO=32;  CIl=32;  dst=0; }
    else if (j < 3072) { int q=j-1024;   co=q>>5;  ci=q&31;  w=w2; CIsrc=32;  CO=64;  CIl=32;  dst=9216; }
    else if (j < 11264){ int q=j-3072;   co=q>>6;  ci=q&63;  w=w3; CIsrc=64;  CO=128; CIl=64;  dst=27648; }
    else if (j < 44032){ int q=j-11264;  co=q>>7;  ci=q&127; w=w4; CIsrc=128; CO=256; CIl=128; dst=101376; }
    else               { int q=j-44032;  co=q>>8;  ci=q&255; w=w5; CIsrc=256; CO=256; CIl=256; dst=396288; }
    #pragma unroll
    for (int k = 0; k < 9; ++k){
      float val = (ci < CIsrc) ? w[(co*CIsrc + ci)*9 + k] : 0.f;
      wbb[dst + (k*CO + co)*CIl + ci] = f2b(val);
    }
  } else if (b < 1964){
    int idx = (b-1452)*256 + tid;
    int m = idx >> 15, rem = idx & 32767, k = rem >> 7, cc = rem & 127;
    const float* sp = (m==0)?a:(m==1)?b2:(m==2)?c2:d2;
    o[m*32768 + k*128 + cc] = sp[cc*256 + k];
  } else {
    int j = (b-1964)*256 + tid;
    const int c0=2056, c1=6184, c2z=10344, c3=14568, c4=18920, ca=35368;
    if (j >= ca) return;
    if (j >= c4){
      int q = j - c4;
      ((float4*)adjz)[q] = make_float4(0.f,0.f,0.f,0.f);
      return;
    }
    int base, P, R, W, per, rem;
    if (j < c0)       { base=0;       P=516; R=514; W=512; per=2056; rem=j; }
    else if (j < c1)  { base=2121792; P=260; R=258; W=256; per=1032; rem=j-c0; }
    else if (j < c2z) { base=4268352; P=132; R=130; W=128; per=520;  rem=j-c1; }
    else if (j < c3)  { base=5366592; P=68;  R=66;  W=64;  per=264;  rem=j-c2z; }
    else              { base=5941056; P=36;  R=34;  W=32;  per=136;  rem=j-c3; }
    int s = rem / per, r2 = rem - s*per;
    int row, px;
    if (r2 < 2*P){ row = (r2 < P) ? 0 : R-1; px = (r2 < P) ? r2 : r2 - P; }
    else { int q = r2 - 2*P; row = 1 + (q >> 1); px = (q & 1) ? (W+1) : 0; }
    *(uint4*)&wsb[(size_t)base + ((size_t)(s*R + row)*P + px)*8] = make_uint4(0,0,0,0);
  }
}

// ---------------- graph kernels (fp32) ----------------
// sage12, 256 threads: agg 1 feature/thread; p1 (tid<128) | p2 (tid>=128) in
// parallel halves (wave-uniform); reductions 256-wide with identity padding.
__global__ __launch_bounds__(256) void sage12_kernel(
    const float* __restrict__ adj, const float* __restrict__ cnt,
    const float* __restrict__ org,
    const float* __restrict__ wl1t, const float* __restrict__ bl1, const float* __restrict__ wr1t,
    const float* __restrict__ wl2t, const float* __restrict__ bl2, const float* __restrict__ wr2t,
    float* __restrict__ x1, float* __restrict__ s_out, float* __restrict__ st,
    float* __restrict__ entpart)
{
  __shared__ float sa[NN1], so[NN1], col[NN1], red[256];
  int n = blockIdx.x, tid = threadIdx.x;
  col[tid] = adj[tid*NN1 + n];
  so[tid]  = org[n*NN1 + tid];
  __syncthreads();
  float a0 = 0.f;
  #pragma unroll 4
  for (int s2 = 0; s2 < NN1; ++s2) a0 += col[s2] * org[s2*NN1 + tid];
  sa[tid] = a0 / fmaxf(cnt[n], 1.0f);
  __syncthreads();

  const int c = tid & 127;
  const bool lo = tid < 128;                  // wave-uniform
  const float* wlt = lo ? wl1t : wl2t;
  const float* wrt = lo ? wr1t : wr2t;
  float p = lo ? bl1[c] : bl2[c];
  for (int k = 0; k < NN1; ++k)
    p += sa[k]*wlt[k*128+c] + so[k]*wrt[k*128+c];

  float n1s = block_sum<256>(lo ? p*p : 0.f, red, tid);
  if (lo) x1[n*128 + c] = p / fmaxf(sqrtf(n1s), 1e-12f);
  float n2s = block_sum<256>(lo ? 0.f : p*p, red, tid);
  float p2n = p / fmaxf(sqrtf(n2s), 1e-12f);
  float mx = block_max<256>(lo ? -INFINITY : p2n, red, tid);
  float ev = expf(p2n - mx);
  float ssum = block_sum<256>(lo ? 0.f : ev, red, tid);
  float sv = ev / ssum;
  if (!lo){
    s_out[n*128 + c] = sv;
    st[c*NN1 + n] = sv;
  }
  float esum = block_sum<256>(lo ? 0.f : (-sv * logf(sv + 1e-15f)), red, tid);
  if (tid == 0) entpart[n] = esum;
}

__global__ __launch_bounds__(256) void fuse1_kernel(
    const float* __restrict__ s, const float* __restrict__ x1,
    const float* __restrict__ adj, const float* __restrict__ st,
    float* __restrict__ xp, float* __restrict__ t, float* __restrict__ linkpart)
{
  __shared__ float sn[128]; __shared__ float red[256];
  int b = blockIdx.x, tid = threadIdx.x;
  if (b < 64){
    int cc = b*2 + (tid >> 7), f = tid & 127;
    float acc = 0.f;
    for (int n = 0; n < NN1; ++n) acc += s[n*128+cc] * x1[n*128+f];
    xp[cc*128+f] = acc;
  } else if (b < 192){
    int n = (b-64)*2 + (tid >> 7), c = tid & 127;
    float acc = 0.f;
    for (int m = 0; m < NN1; ++m){
      float a = adj[n*NN1+m];
      if (a != 0.f) acc += a * s[m*128+c];
    }
    t[n*128+c] = acc;
  } else {
    int n = b - 192, m = tid;
    if (m < 128) sn[m] = s[n*128+m];
    __syncthreads();
    float dot = 0.f;
    for (int c = 0; c < 128; ++c) dot += sn[c]*st[c*NN1 + m];
    float v = adj[n*NN1+m] - dot;
    float part = block_sum<256>(v*v, red, m);
    if (m == 0) linkpart[n] = part;
  }
}

// adjp row + binarize, 256 threads: n-sum split into two halves per j.
__global__ __launch_bounds__(256) void adjp_bin_kernel(
    const float* __restrict__ s, const float* __restrict__ t,
    float* __restrict__ edge_out, float* __restrict__ ei2_out, int* __restrict__ cols)
{
  __shared__ float scol[NN1]; __shared__ float red[256]; __shared__ int redi[256];
  int cc = blockIdx.x, tid = threadIdx.x;
  int j = tid & 127, h = tid >> 7;
  scol[tid] = s[tid*128 + cc];
  __syncthreads();
  float part = 0.f;
  for (int n = h*128; n < (h+1)*128; ++n) part += scol[n] * t[n*128 + j];
  red[tid] = part; __syncthreads();
  float acc = red[j] + red[j+128];
  __syncthreads();
  float mx = block_max<256>(acc, red, tid);            // duplicates harmless
  if (h == 0) edge_out[cc*128+j] = (acc == mx) ? 1.0f : 0.0f;
  int cand = (acc == mx) ? j : (1 << 30);
  int cmin = block_min_int<256>(cand, redi, tid);
  if (tid == 0){
    cols[cc] = cmin;
    ei2_out[cc] = (float)cc;
    ei2_out[128 + cc] = (float)cmin;
  }
}

__global__ __launch_bounds__(128) void sage3_kernel(
    const float* __restrict__ xp, const int* __restrict__ cols,
    const float* __restrict__ wl3, const float* __restrict__ bl3,
    const float* __restrict__ wr3, float* __restrict__ nodes_out)
{
  __shared__ int colsl[NN2]; __shared__ float red[128];
  int n = blockIdx.x, f = threadIdx.x;
  colsl[f] = cols[f];
  __syncthreads();
  float acc = 0.f, c = 0.f;
  for (int i = 0; i < NN2; ++i){
    if (colsl[i] == n){ acc += xp[i*128+f]; c += 1.f; }
  }
  float ag = acc / fmaxf(c, 1.f);
  float xv = xp[n*128+f];
  float q0 = block_sum<128>(ag*wl3[f]     + xv*wr3[f],     red, f);
  float q1 = block_sum<128>(ag*wl3[128+f] + xv*wr3[128+f], red, f);
  if (f == 0){
    float p0 = q0 + bl3[0], p1 = q1 + bl3[1];
    float nm = fmaxf(sqrtf(p0*p0 + p1*p1), 1e-12f);
    nodes_out[n*2+0] = tanhf(p0/nm);
    nodes_out[n*2+1] = tanhf(p1/nm);
  }
}

__global__ __launch_bounds__(256) void finalize_kernel(const float* __restrict__ linkpart,
    const float* __restrict__ entpart, float* __restrict__ d_out)
{
  __shared__ float red[256];
  int t = threadIdx.x;
  float ls = block_sum<256>(linkpart[t], red, t);
  float es = block_sum<256>(entpart[t], red, t);
  float v0 = 0.f, v1 = 0.f;
  if (t < 128){ v0 = d_out[4 + t*2 + 0]; v1 = d_out[4 + t*2 + 1]; }
  float s0 = block_sum<256>(v0, red, t);
  float s1 = block_sum<256>(v1, red, t);
  if (t == 0){
    d_out[0] = s0;
    d_out[1] = s1;
    d_out[2] = sqrtf(ls)/65536.0f + sqrtf(16256.0f)/16384.0f;  // ll1 + ll2(const)
    d_out[3] = es/256.0f;                                      // el1 + el2(=0)
  }
}

extern "C" void kernel_launch(void* const* d_in, const int* in_sizes, int n_in,
                              void* d_out_v, int out_size, void* d_ws, size_t ws_size,
                              hipStream_t stream)
{
  (void)in_sizes; (void)n_in; (void)out_size; (void)ws_size;
  const float* input = (const float*)d_in[0];
  const int*   ei    = (const int*)  d_in[1];
  const float* w1 = (const float*)d_in[2];  const float* b1 = (const float*)d_in[3];
  const float* w2 = (const float*)d_in[4];  const float* b2 = (const float*)d_in[5];
  const float* w3 = (const float*)d_in[6];  const float* b3 = (const float*)d_in[7];
  const float* w4 = (const float*)d_in[8];  const float* b4 = (const float*)d_in[9];
  const float* w5 = (const float*)d_in[10]; const float* b5 = (const float*)d_in[11];
  const float* s1wl = (const float*)d_in[12]; const float* s1bl = (const float*)d_in[13];
  const float* s1wr = (const float*)d_in[14];
  const float* s2wl = (const float*)d_in[15]; const float* s2bl = (const float*)d_in[16];
  const float* s2wr = (const float*)d_in[17];
  const float* s3wl = (const float*)d_in[18]; const float* s3bl = (const float*)d_in[19];
  const float* s3wr = (const float*)d_in[20];
  float* d_out = (float*)d_out_v;
  float* ws = (float*)d_ws;

  unsigned short* P0b = (unsigned short*)(ws);
  unsigned short* Pb1 = (unsigned short*)(ws + 1060896);
  unsigned short* Pb2 = (unsigned short*)(ws + 2134176);
  unsigned short* Pb3 = (unsigned short*)(ws + 2683296);
  unsigned short* Pb4 = (unsigned short*)(ws + 2970528);
  unsigned short* wb  = (unsigned short*)(ws + 3127200);
  float* org = ws + 3620256;
  float* wt  = ws + 3685792;
  float* st  = ws + 3816864;
  float* G   = ws + 3849632;

  float* adj1     = G;
  float* cnt      = G + 65536;
  float* x1       = G + 147712;
  float* s        = G + 180480;
  float* t        = G + 213248;
  float* xp       = G + 246016;
  int*   cols     = (int*)(G + 278784);
  float* linkpart = G + 278912;
  float* entpart  = G + 279168;
  float* PART     = ws + 4129280;   // 2,097,152 f32 (split-K partials, L4 then L5)

  // prep: input pack (1024) + conv weights (428) + sage wT (512) + zeroing (139)
  prep_kernel<<<dim3(2103), 256, 0, stream>>>(input, P0b, w1, w2, w3, w4, w5, wb,
                                              s1wl, s1wr, s2wl, s2wr, wt,
                                              (unsigned short*)ws, adj1);

  // conv stack (bf16 MFMA; L4/L5 split-K over grid.z)
  conv_mfma<1,32,32,1,0,0>      <<<dim3(32,32),   256, 0, stream>>>(P0b, wb,        b1, Pb1, nullptr, 516, 2121792, 260, 536640);
  conv_mfma<1,64,32,4,2600,0>   <<<dim3(32,16),   256, 0, stream>>>(Pb1, wb+9216,   b2, Pb2, nullptr, 260, 536640, 132, 137280);
  conv_mfma<2,128,64,4,2600,0>  <<<dim3(32,8),    256, 0, stream>>>(Pb2, wb+27648,  b3, Pb3, nullptr, 132, 137280, 68,  35904);
  conv_mfma<2,256,128,4,2600,2> <<<dim3(32,4,2),  256, 0, stream>>>(Pb3, wb+101376, b4, nullptr, PART, 68, 35904, 64, 0);
  reduce_pool_b<2>              <<<dim3(1024),    256, 0, stream>>>(PART, b4, Pb4, 256, 64, 64, 36, 9792);
  conv_mfma<1,256,256,4,2600,2> <<<dim3(16,2,8),  256, 0, stream>>>(Pb4, wb+396288, b5, nullptr, PART, 36, 9792, 32, 0);
  // L5 reduce + build_adj fused (adj zeroed by prep)
  reduce5_adj_kernel            <<<dim3(272),     256, 0, stream>>>(PART, b5, org, ei, adj1, cnt);

  // graph tail (fp32)
  sage12_kernel   <<<dim3(256), 256, 0, stream>>>(adj1, cnt, org, wt, s1bl, wt+32768,
                                                  wt+65536, s2bl, wt+98304, x1, s, st, entpart);
  fuse1_kernel    <<<dim3(448), 256, 0, stream>>>(s, x1, adj1, st, xp, t, linkpart);
  adjp_bin_kernel <<<dim3(128), 256, 0, stream>>>(s, t, d_out + 260, d_out + 16644, cols);
  sage3_kernel    <<<dim3(128), 128, 0, stream>>>(xp, cols, s3wl, s3bl, s3wr, d_out + 4);
  finalize_kernel <<<dim3(1),   256, 0, stream>>>(linkpart, entpart, d_out);
}

// Round 19
// 178.654 us; speedup vs baseline: 1.1195x; 1.1195x over previous
//
#include <hip/hip_runtime.h>
#include <hip/hip_bf16.h>
#include <math.h>

#define N_EDGES 4096
#define NN1 256
#define NN2 128

typedef short v8s __attribute__((ext_vector_type(8)));
typedef float v4f __attribute__((ext_vector_type(4)));

__device__ inline unsigned short f2b(float f){
  union { __hip_bfloat16 h; unsigned short u; } cv;
  cv.h = __float2bfloat16(f);
  return cv.u;
}

// ---------------- reduction helpers ----------------
template<int NT>
__device__ inline float block_sum(float v, float* red, int t){
  red[t] = v; __syncthreads();
  #pragma unroll
  for (int st = NT/2; st > 0; st >>= 1){
    if (t < st) red[t] += red[t+st];
    __syncthreads();
  }
  float r = red[0]; __syncthreads();
  return r;
}
template<int NT>
__device__ inline float block_max(float v, float* red, int t){
  red[t] = v; __syncthreads();
  #pragma unroll
  for (int st = NT/2; st > 0; st >>= 1){
    if (t < st) red[t] = fmaxf(red[t], red[t+st]);
    __syncthreads();
  }
  float r = red[0]; __syncthreads();
  return r;
}
template<int NT>
__device__ inline int block_min_int(int v, int* red, int t){
  red[t] = v; __syncthreads();
  #pragma unroll
  for (int st = NT/2; st > 0; st >>= 1){
    if (t < st) red[t] = min(red[t], red[t+st]);
    __syncthreads();
  }
  int r = red[0]; __syncthreads();
  return r;
}

// ---------------- conv3x3(SAME) via bf16 MFMA implicit GEMM (r13 template + split-K) --
// OUTMODE: 0 = bf16 slab out (pool fused), 1 = f32 org out (pool fused),
//          2 = f32 conv partials [z][COUT][W][W] (no pool/bias; split-K over grid.z).
template<int CHUNKS, int COUT, int CIN, int SSLABS, int BSTR, int OUTMODE>
__global__ __launch_bounds__(256) void conv_mfma(
    const unsigned short* __restrict__ in, const unsigned short* __restrict__ wb,
    const float* __restrict__ bias, unsigned short* __restrict__ outb,
    float* __restrict__ outf,
    int in_row, int in_slab, int out_row, int out_slab)
{
  constexpr int CG = COUT/32;
  __shared__ unsigned short tileb[SSLABS*2600];
  __shared__ unsigned short wldsb[9*32*40];

  const int cg = blockIdx.x % CG, bx = blockIdx.x / CG, by = blockIdx.y;
  const int z = blockIdx.z;
  const int cbase = z*CHUNKS;
  const int tid = threadIdx.x, lane = tid & 63, wv = tid >> 6;
  const int cot = wv >> 1, wp = wv & 1;
  const int ml = lane & 15, g = lane >> 4;

  v4f acc[8];
  #pragma unroll
  for (int t = 0; t < 8; ++t) acc[t] = (v4f){0.f,0.f,0.f,0.f};

  for (int cb = 0; cb < CHUNKS; ++cb){
    if (cb) __syncthreads();
    for (int j = tid; j < SSLABS*324; j += 256){
      int s = j / 324, rem = j - s*324;
      int row = rem / 18, px = rem - row*18;
      int gidx = ((cbase+cb)*SSLABS + s)*in_slab + ((by*16 + row)*in_row + bx*16 + px)*8;
      *(v8s*)&tileb[s*2600 + (row*18+px)*8] = *(const v8s*)&in[gidx];
    }
    for (int j = tid; j < 1152; j += 256){
      int k = j >> 7, rem = j & 127;
      int co = rem >> 2, q = rem & 3;
      int gw = (k*COUT + cg*32 + co)*CIN + (cbase+cb)*32 + q*8;
      *(v8s*)&wldsb[(k*32+co)*40 + q*8] = *(const v8s*)&wb[gw];
    }
    __syncthreads();

    #pragma unroll
    for (int k9 = 0; k9 < 9; ++k9){
      const int ky = k9/3, kx = k9 - 3*(k9/3);
      v8s a = *(const v8s*)&wldsb[(k9*32 + cot*16 + ml)*40 + g*8];
      #pragma unroll
      for (int tt = 0; tt < 8; ++tt){
        int t = wp*8 + tt;
        v8s b = *(const v8s*)&tileb[g*BSTR + ((t+ky)*18 + kx + ml)*8];
        acc[tt] = __builtin_amdgcn_mfma_f32_16x16x32_bf16(a, b, acc[tt], 0, 0, 0);
      }
    }
  }

  const int cob = cg*32 + cot*16 + g*4;
  if (OUTMODE == 2){
    const int W = out_row;
    #pragma unroll
    for (int tt = 0; tt < 8; ++tt){
      int gy = by*16 + wp*8 + tt, gx = bx*16 + ml;
      #pragma unroll
      for (int r = 0; r < 4; ++r)
        outf[((size_t)(z*COUT + cob + r)*W + gy)*W + gx] = acc[tt][r];
    }
    return;
  }

  float b4[4] = {bias[cob], bias[cob+1], bias[cob+2], bias[cob+3]};
  #pragma unroll
  for (int tp = 0; tp < 4; ++tp){
    float m[4];
    #pragma unroll
    for (int r = 0; r < 4; ++r){
      float v = fmaxf(acc[2*tp][r], acc[2*tp+1][r]);
      float o = __shfl_xor(v, 1);
      m[r] = fmaxf(fmaxf(v, o) + b4[r], 0.f);
    }
    if ((lane & 1) == 0){
      int gy = by*8 + wp*4 + tp, gx = bx*8 + (ml >> 1);
      if (OUTMODE == 1){
        #pragma unroll
        for (int r = 0; r < 4; ++r)
          outf[(cob + r)*256 + gy*16 + gx] = m[r];
      } else {
        unsigned int u0 = (unsigned)f2b(m[0]) | ((unsigned)f2b(m[1]) << 16);
        unsigned int u1 = (unsigned)f2b(m[2]) | ((unsigned)f2b(m[3]) << 16);
        int slabo = cob >> 3, sub = (g & 1)*4;
        size_t idx = (size_t)slabo*out_slab + (size_t)((gy+1)*out_row + gx+1)*8 + sub;
        *(uint2*)(outb + idx) = make_uint2(u0, u1);
      }
    }
  }
}

// sum f32 partials over splits (ascending), then bias + relu + maxpool2x2.
// OUTF32=1 -> f32 [COUT][OH][OW] (org); else bf16 slab-packed (pitch out_row/out_slab).
template<int SPLITK, int OUTF32>
__global__ __launch_bounds__(256) void reduce_pool(
    const float* __restrict__ pbuf, const float* __restrict__ bias,
    unsigned short* __restrict__ outb, float* __restrict__ outf,
    int COUT, int H, int W, int out_row, int out_slab)
{
  int idx = blockIdx.x*256 + threadIdx.x;
  const int OW = W >> 1, OH = H >> 1;
  if (idx >= COUT*OH*OW) return;
  int px = idx % OW; int t2 = idx / OW; int py = t2 % OH; int cout = t2 / OH;
  size_t base = ((size_t)cout*H + 2*py)*W + 2*px;
  size_t sstr = (size_t)COUT*H*W;
  float s00=0.f, s01=0.f, s10=0.f, s11=0.f;
  #pragma unroll
  for (int s = 0; s < SPLITK; ++s){
    const float* pb = pbuf + s*sstr + base;
    s00 += pb[0]; s01 += pb[1]; s10 += pb[W]; s11 += pb[W+1];
  }
  float m = fmaxf(fmaxf(fmaxf(s00,s01), fmaxf(s10,s11)) + bias[cout], 0.f);
  if (OUTF32){
    outf[cout*OH*OW + py*OW + px] = m;
  } else {
    outb[(size_t)(cout>>3)*out_slab + (size_t)((py+1)*out_row + px+1)*8 + (cout&7)] = f2b(m);
  }
}

// ---------------- prep: input pack + weight cvt + sage wT + border/adj zero ----------
__global__ __launch_bounds__(256) void prep_kernel(
    const float* __restrict__ src, unsigned short* __restrict__ p0b,
    const float* __restrict__ w1, const float* __restrict__ w2,
    const float* __restrict__ w3, const float* __restrict__ w4,
    const float* __restrict__ w5, unsigned short* __restrict__ wbb,
    const float* __restrict__ a, const float* __restrict__ b2,
    const float* __restrict__ c2, const float* __restrict__ d2,
    float* __restrict__ o, unsigned short* __restrict__ wsb,
    float* __restrict__ adjz)
{
  int b = blockIdx.x, tid = threadIdx.x;
  if (b < 1024){
    int idx = b*256 + tid;
    int y = idx >> 9, x = idx & 511;
    unsigned short v8[8];
    #pragma unroll
    for (int c = 0; c < 5; ++c) v8[c] = f2b(src[c*262144 + y*512 + x]);
    v8[5] = 0; v8[6] = 0; v8[7] = 0;
    *(uint4*)&p0b[((size_t)(y+1)*516 + (x+1))*8] = *(uint4*)v8;
  } else if (b < 1452){
    int j = (b-1024)*256 + tid;
    int co, ci, CO, CIl, CIsrc, dst; const float* w;
    if (j < 1024)      { co=j>>5;        ci=j&31;        w=w1; CIsrc=5;   CO=32;  CIl=32;  dst=0; }
    else if (j < 3072) { int q=j-1024;   co=q>>5;  ci=q&31;  w=w2; CIsrc=32;  CO=64;  CIl=32;  dst=9216; }
    else if (j < 11264){ int q=j-3072;   co=q>>6;  ci=q&63;  w=w3; CIsrc=64;  CO=128; CIl=64;  dst=27648; }
    else if (j < 44032){ int q=j-11264;  co=q>>7;  ci=q&127; w=w4; CIsrc=128; CO=256; CIl=128; dst=101376; }
    else               { int q=j-44032;  co=q>>8;  ci=q&255; w=w5; CIsrc=256; CO=256; CIl=256; dst=396288; }
    #pragma unroll
    for (int k = 0; k < 9; ++k){
      float val = (ci < CIsrc) ? w[(co*CIsrc + ci)*9 + k] : 0.f;
      wbb[dst + (k*CO + co)*CIl + ci] = f2b(val);
    }
  } else if (b < 1964){
    int idx = (b-1452)*256 + tid;
    int m = idx >> 15, rem = idx & 32767, k = rem >> 7, cc = rem & 127;
    const float* sp = (m==0)?a:(m==1)?b2:(m==2)?c2:d2;
    o[m*32768 + k*128 + cc] = sp[cc*256 + k];
  } else {
    int j = (b-1964)*256 + tid;
    const int c0=2056, c1=6184, c2z=10344, c3=14568, c4=18920, ca=35368;
    if (j >= ca) return;
    if (j >= c4){
      int q = j - c4;
      ((float4*)adjz)[q] = make_float4(0.f,0.f,0.f,0.f);
      return;
    }
    int base, P, R, W, per, rem;
    if (j < c0)       { base=0;       P=516; R=514; W=512; per=2056; rem=j; }
    else if (j < c1)  { base=2121792; P=260; R=258; W=256; per=1032; rem=j-c0; }
    else if (j < c2z) { base=4268352; P=132; R=130; W=128; per=520;  rem=j-c1; }
    else if (j < c3)  { base=5366592; P=68;  R=66;  W=64;  per=264;  rem=j-c2z; }
    else              { base=5941056; P=36;  R=34;  W=32;  per=136;  rem=j-c3; }
    int s = rem / per, r2 = rem - s*per;
    int row, px;
    if (r2 < 2*P){ row = (r2 < P) ? 0 : R-1; px = (r2 < P) ? r2 : r2 - P; }
    else { int q = r2 - 2*P; row = 1 + (q >> 1); px = (q & 1) ? (W+1) : 0; }
    *(uint4*)&wsb[(size_t)base + ((size_t)(s*R + row)*P + px)*8] = make_uint4(0,0,0,0);
  }
}

// ---------------- graph kernels (fp32, r13-proven) ----------------
__global__ void build_adj_kernel(const int* __restrict__ ei, float* adj, float* cnt){
  int e = blockIdx.x*256 + threadIdx.x;
  if (e < N_EDGES){
    int s = ei[e], d = ei[N_EDGES + e];
    atomicAdd(&adj[s*NN1 + d], 1.0f);
    atomicAdd(&cnt[d], 1.0f);
  }
}

__global__ __launch_bounds__(128) void sage12_kernel(
    const float* __restrict__ adj, const float* __restrict__ cnt,
    const float* __restrict__ org,
    const float* __restrict__ wl1t, const float* __restrict__ bl1, const float* __restrict__ wr1t,
    const float* __restrict__ wl2t, const float* __restrict__ bl2, const float* __restrict__ wr2t,
    float* __restrict__ x1, float* __restrict__ s_out, float* __restrict__ st,
    float* __restrict__ entpart)
{
  __shared__ float sa[NN1], so[NN1], col[NN1], red[128];
  int n = blockIdx.x, c = threadIdx.x;
  for (int k = c; k < NN1; k += 128){
    col[k] = adj[k*NN1 + n];
    so[k]  = org[n*NN1 + k];
  }
  __syncthreads();
  float a0 = 0.f, a1 = 0.f;
  #pragma unroll 4
  for (int s2 = 0; s2 < NN1; ++s2){
    float av = col[s2];
    a0 += av * org[s2*NN1 + c];
    a1 += av * org[s2*NN1 + c + 128];
  }
  float cd = fmaxf(cnt[n], 1.0f);
  sa[c] = a0 / cd;
  sa[c+128] = a1 / cd;
  __syncthreads();

  float p1 = bl1[c], p2 = bl2[c];
  for (int k = 0; k < NN1; ++k){
    float av = sa[k], ov = so[k];
    p1 += av*wl1t[k*128+c] + ov*wr1t[k*128+c];
    p2 += av*wl2t[k*128+c] + ov*wr2t[k*128+c];
  }
  float n1s = block_sum<128>(p1*p1, red, c);
  x1[n*128 + c] = p1 / fmaxf(sqrtf(n1s), 1e-12f);
  float n2s = block_sum<128>(p2*p2, red, c);
  float p2n = p2 / fmaxf(sqrtf(n2s), 1e-12f);
  float mx = block_max<128>(p2n, red, c);
  float ev = expf(p2n - mx);
  float ssum = block_sum<128>(ev, red, c);
  float sv = ev / ssum;
  s_out[n*128 + c] = sv;
  st[c*NN1 + n] = sv;
  float esum = block_sum<128>(-sv * logf(sv + 1e-15f), red, c);
  if (c == 0) entpart[n] = esum;
}

__global__ __launch_bounds__(256) void fuse1_kernel(
    const float* __restrict__ s, const float* __restrict__ x1,
    const float* __restrict__ adj, const float* __restrict__ st,
    float* __restrict__ xp, float* __restrict__ t, float* __restrict__ linkpart)
{
  __shared__ float sn[128]; __shared__ float red[256];
  int b = blockIdx.x, tid = threadIdx.x;
  if (b < 64){
    int cc = b*2 + (tid >> 7), f = tid & 127;
    float acc = 0.f;
    for (int n = 0; n < NN1; ++n) acc += s[n*128+cc] * x1[n*128+f];
    xp[cc*128+f] = acc;
  } else if (b < 192){
    int n = (b-64)*2 + (tid >> 7), c = tid & 127;
    float acc = 0.f;
    for (int m = 0; m < NN1; ++m){
      float a = adj[n*NN1+m];
      if (a != 0.f) acc += a * s[m*128+c];
    }
    t[n*128+c] = acc;
  } else {
    int n = b - 192, m = tid;
    if (m < 128) sn[m] = s[n*128+m];
    __syncthreads();
    float dot = 0.f;
    for (int c = 0; c < 128; ++c) dot += sn[c]*st[c*NN1 + m];
    float v = adj[n*NN1+m] - dot;
    float part = block_sum<256>(v*v, red, m);
    if (m == 0) linkpart[n] = part;
  }
}

__global__ __launch_bounds__(128) void adjp_bin_kernel(
    const float* __restrict__ s, const float* __restrict__ t,
    float* __restrict__ edge_out, float* __restrict__ ei2_out, int* __restrict__ cols)
{
  __shared__ float scol[NN1]; __shared__ float red[128]; __shared__ int redi[128];
  int cc = blockIdx.x, j = threadIdx.x;
  scol[j]       = s[j*128 + cc];
  scol[j + 128] = s[(j+128)*128 + cc];
  __syncthreads();
  float acc = 0.f;
  for (int n = 0; n < NN1; ++n) acc += scol[n] * t[n*128 + j];
  float mx = block_max<128>(acc, red, j);
  edge_out[cc*128+j] = (acc == mx) ? 1.0f : 0.0f;
  int cand = (acc == mx) ? j : (1 << 30);
  int cmin = block_min_int<128>(cand, redi, j);
  if (j == 0){
    cols[cc] = cmin;
    ei2_out[cc] = (float)cc;
    ei2_out[128 + cc] = (float)cmin;
  }
}

__global__ __launch_bounds__(128) void sage3_kernel(
    const float* __restrict__ xp, const int* __restrict__ cols,
    const float* __restrict__ wl3, const float* __restrict__ bl3,
    const float* __restrict__ wr3, float* __restrict__ nodes_out)
{
  __shared__ int colsl[NN2]; __shared__ float red[128];
  int n = blockIdx.x, f = threadIdx.x;
  colsl[f] = cols[f];
  __syncthreads();
  float acc = 0.f, c = 0.f;
  for (int i = 0; i < NN2; ++i){
    if (colsl[i] == n){ acc += xp[i*128+f]; c += 1.f; }
  }
  float ag = acc / fmaxf(c, 1.f);
  float xv = xp[n*128+f];
  float q0 = block_sum<128>(ag*wl3[f]     + xv*wr3[f],     red, f);
  float q1 = block_sum<128>(ag*wl3[128+f] + xv*wr3[128+f], red, f);
  if (f == 0){
    float p0 = q0 + bl3[0], p1 = q1 + bl3[1];
    float nm = fmaxf(sqrtf(p0*p0 + p1*p1), 1e-12f);
    nodes_out[n*2+0] = tanhf(p0/nm);
    nodes_out[n*2+1] = tanhf(p1/nm);
  }
}

__global__ __launch_bounds__(256) void finalize_kernel(const float* __restrict__ linkpart,
    const float* __restrict__ entpart, float* __restrict__ d_out)
{
  __shared__ float red[256];
  int t = threadIdx.x;
  float ls = block_sum<256>(linkpart[t], red, t);
  float es = block_sum<256>(entpart[t], red, t);
  float v0 = 0.f, v1 = 0.f;
  if (t < 128){ v0 = d_out[4 + t*2 + 0]; v1 = d_out[4 + t*2 + 1]; }
  float s0 = block_sum<256>(v0, red, t);
  float s1 = block_sum<256>(v1, red, t);
  if (t == 0){
    d_out[0] = s0;
    d_out[1] = s1;
    d_out[2] = sqrtf(ls)/65536.0f + sqrtf(16256.0f)/16384.0f;  // ll1 + ll2(const)
    d_out[3] = es/256.0f;                                      // el1 + el2(=0)
  }
}

extern "C" void kernel_launch(void* const* d_in, const int* in_sizes, int n_in,
                              void* d_out_v, int out_size, void* d_ws, size_t ws_size,
                              hipStream_t stream)
{
  (void)in_sizes; (void)n_in; (void)out_size; (void)ws_size;
  const float* input = (const float*)d_in[0];
  const int*   ei    = (const int*)  d_in[1];
  const float* w1 = (const float*)d_in[2];  const float* b1 = (const float*)d_in[3];
  const float* w2 = (const float*)d_in[4];  const float* b2 = (const float*)d_in[5];
  const float* w3 = (const float*)d_in[6];  const float* b3 = (const float*)d_in[7];
  const float* w4 = (const float*)d_in[8];  const float* b4 = (const float*)d_in[9];
  const float* w5 = (const float*)d_in[10]; const float* b5 = (const float*)d_in[11];
  const float* s1wl = (const float*)d_in[12]; const float* s1bl = (const float*)d_in[13];
  const float* s1wr = (const float*)d_in[14];
  const float* s2wl = (const float*)d_in[15]; const float* s2bl = (const float*)d_in[16];
  const float* s2wr = (const float*)d_in[17];
  const float* s3wl = (const float*)d_in[18]; const float* s3bl = (const float*)d_in[19];
  const float* s3wr = (const float*)d_in[20];
  float* d_out = (float*)d_out_v;
  float* ws = (float*)d_ws;

  unsigned short* P0b = (unsigned short*)(ws);
  unsigned short* Pb1 = (unsigned short*)(ws + 1060896);
  unsigned short* Pb2 = (unsigned short*)(ws + 2134176);
  unsigned short* Pb3 = (unsigned short*)(ws + 2683296);
  unsigned short* Pb4 = (unsigned short*)(ws + 2970528);
  unsigned short* wb  = (unsigned short*)(ws + 3127200);
  float* org = ws + 3620256;
  float* wt  = ws + 3685792;
  float* st  = ws + 3816864;
  float* G   = ws + 3849632;

  float* adj1     = G;
  float* cnt      = G + 65536;
  float* x1       = G + 147712;
  float* s        = G + 180480;
  float* t        = G + 213248;
  float* xp       = G + 246016;
  int*   cols     = (int*)(G + 278784);
  float* linkpart = G + 278912;
  float* entpart  = G + 279168;
  float* PART     = ws + 4129280;   // 2,097,152 f32 (split-K partials, L4 then L5)

  // prep: input pack (1024) + conv weights (428) + sage wT (512) + zeroing (139)
  prep_kernel<<<dim3(2103), 256, 0, stream>>>(input, P0b, w1, w2, w3, w4, w5, wb,
                                              s1wl, s1wr, s2wl, s2wr, wt,
                                              (unsigned short*)ws, adj1);

  // conv stack (bf16 MFMA, r13 template; L4/L5 split-K over grid.z)
  conv_mfma<1,32,32,1,0,0>      <<<dim3(32,32),   256, 0, stream>>>(P0b, wb,        b1, Pb1, nullptr, 516, 2121792, 260, 536640);
  conv_mfma<1,64,32,4,2600,0>   <<<dim3(32,16),   256, 0, stream>>>(Pb1, wb+9216,   b2, Pb2, nullptr, 260, 536640, 132, 137280);
  conv_mfma<2,128,64,4,2600,0>  <<<dim3(32,8),    256, 0, stream>>>(Pb2, wb+27648,  b3, Pb3, nullptr, 132, 137280, 68,  35904);
  // L4: splitK2 -> PART [2][256][64][64], reduce -> Pb4 (bf16 slab, pitch 36/9792)
  conv_mfma<2,256,128,4,2600,2> <<<dim3(32,4,2),  256, 0, stream>>>(Pb3, wb+101376, b4, nullptr, PART, 68, 35904, 64, 0);
  reduce_pool<2,0>              <<<dim3(1024),    256, 0, stream>>>(PART, b4, Pb4, nullptr, 256, 64, 64, 36, 9792);
  // L5: splitK8 -> PART [8][256][32][32], reduce -> org (f32)
  conv_mfma<1,256,256,4,2600,2> <<<dim3(16,2,8),  256, 0, stream>>>(Pb4, wb+396288, b5, nullptr, PART, 36, 9792, 32, 0);
  reduce_pool<8,1>              <<<dim3(256),     256, 0, stream>>>(PART, b5, nullptr, org, 256, 32, 32, 0, 0);

  // graph tail (fp32, separate kernels - r13-proven)
  build_adj_kernel<<<dim3(16),  256, 0, stream>>>(ei, adj1, cnt);
  sage12_kernel   <<<dim3(256), 128, 0, stream>>>(adj1, cnt, org, wt, s1bl, wt+32768,
                                                  wt+65536, s2bl, wt+98304, x1, s, st, entpart);
  fuse1_kernel    <<<dim3(448), 256, 0, stream>>>(s, x1, adj1, st, xp, t, linkpart);
  adjp_bin_kernel <<<dim3(128), 128, 0, stream>>>(s, t, d_out + 260, d_out + 16644, cols);
  sage3_kernel    <<<dim3(128), 128, 0, stream>>>(xp, cols, s3wl, s3bl, s3wr, d_out + 4);
  finalize_kernel <<<dim3(1),   256, 0, stream>>>(linkpart, entpart, d_out);
}